// Round 1
// 622.284 us; speedup vs baseline: 1.0160x; 1.0160x over previous
//
#include <hip/hip_runtime.h>
#include <hip/hip_bf16.h>

// Problem constants (B=4,T=2048,M=1024,E=8,H=4096) — fp32 in/out
#define S_TOK 8192
#define MDIM  1024
#define EXP   8
#define HDIM  4096
#define CAP   1024   // s // E, capacity_factor = 1.0

typedef __attribute__((ext_vector_type(8))) short short8;
typedef __attribute__((ext_vector_type(4))) float floatx4;

__device__ __forceinline__ unsigned short f2b(float f) {
    union { float f; unsigned int i; } v; v.f = f;
    unsigned int r = v.i + 0x7fffu + ((v.i >> 16) & 1u);  // RNE
    return (unsigned short)(r >> 16);
}

// async global->LDS, 16B per lane, wave-uniform LDS base (HW adds lane*16)
__device__ __forceinline__ void gl2lds16(const unsigned short* g, unsigned short* l) {
    __builtin_amdgcn_global_load_lds(
        (const __attribute__((address_space(1))) unsigned int*)g,
        (__attribute__((address_space(3))) unsigned int*)l,
        16, 0, 0);
}

// ---------------- Kernel 1: gating (pure fp32 — argmax must match np ref) ----
__global__ __launch_bounds__(256) void gate_kernel(
    const float* __restrict__ x, const float* __restrict__ wg,
    float* __restrict__ gates8, int* __restrict__ token_expert)
{
    const int wave = threadIdx.x >> 6, lane = threadIdx.x & 63;
    const int s = blockIdx.x * 4 + wave;

    const float* xr = x + (size_t)s * MDIM + lane * 16;
    float xv[16];
#pragma unroll
    for (int q = 0; q < 4; ++q) *(float4*)(xv + q * 4) = *(const float4*)(xr + q * 4);

    float acc[EXP];
#pragma unroll
    for (int e = 0; e < EXP; ++e) acc[e] = 0.f;
    const int m0 = lane * 16;
#pragma unroll
    for (int j = 0; j < 16; ++j) {
        const float xm = xv[j];
        const float* wr = wg + (size_t)(m0 + j) * EXP;
        float4 w0 = *(const float4*)(wr);
        float4 w1v = *(const float4*)(wr + 4);
        acc[0] += xm * w0.x; acc[1] += xm * w0.y; acc[2] += xm * w0.z; acc[3] += xm * w0.w;
        acc[4] += xm * w1v.x; acc[5] += xm * w1v.y; acc[6] += xm * w1v.z; acc[7] += xm * w1v.w;
    }
#pragma unroll
    for (int e = 0; e < EXP; ++e) {
#pragma unroll
        for (int off = 32; off > 0; off >>= 1)
            acc[e] += __shfl_down(acc[e], off);
    }
    if (lane == 0) {
        float mx = acc[0]; int idx = 0;
#pragma unroll
        for (int e = 1; e < EXP; ++e) if (acc[e] > mx) { mx = acc[e]; idx = e; }
        float g[EXP]; float sum = 0.f;
#pragma unroll
        for (int e = 0; e < EXP; ++e) { g[e] = expf(acc[e] - mx); sum += g[e]; }
        float inv = 1.f / sum;
#pragma unroll
        for (int e = 0; e < EXP; ++e) gates8[(size_t)s * EXP + e] = g[e] * inv;
        token_expert[s] = idx;
    }
}

// ---------------- Kernel 2: scan / slot assignment / l_aux ----------------
__global__ __launch_bounds__(256) void scan_kernel(
    const float* __restrict__ gates8, const int* __restrict__ token_expert,
    int* __restrict__ slot_token, float* __restrict__ slot_gate,
    float* __restrict__ laux_out)
{
    __shared__ int   cnt[256][EXP];
    __shared__ float fsum[256][EXP];
    __shared__ int   tot[EXP];
    const int t = threadIdx.x;

    for (int i = t; i < EXP * CAP; i += 256) slot_token[i] = -1;

    int local[EXP];
#pragma unroll
    for (int e = 0; e < EXP; ++e) local[e] = 0;
    const int s0 = t * 32;
    for (int j = 0; j < 32; ++j) local[token_expert[s0 + j]]++;
#pragma unroll
    for (int e = 0; e < EXP; ++e) cnt[t][e] = local[e];
    __syncthreads();

    if (t < EXP) {
        int run = 0;
        for (int i = 0; i < 256; ++i) { int v = cnt[i][t]; cnt[i][t] = run; run += v; }
        tot[t] = run;  // pre-drop count -> ce
    }
    __syncthreads();

    int off[EXP];
#pragma unroll
    for (int e = 0; e < EXP; ++e) off[e] = cnt[t][e];
    for (int j = 0; j < 32; ++j) {
        int s = s0 + j;
        int e = token_expert[s];
        int loc = off[e]++;
        if (loc < CAP) {
            int slot = e * CAP + loc;
            slot_token[slot] = s;
            slot_gate[slot]  = gates8[(size_t)s * EXP + e];
        }
    }

    float ms[EXP];
#pragma unroll
    for (int e = 0; e < EXP; ++e) ms[e] = 0.f;
    for (int j = 0; j < 32; ++j) {
        const float* g = gates8 + (size_t)(s0 + j) * EXP;
#pragma unroll
        for (int e = 0; e < EXP; ++e) ms[e] += g[e];
    }
#pragma unroll
    for (int e = 0; e < EXP; ++e) fsum[t][e] = ms[e];
    __syncthreads();
    for (int st = 128; st > 0; st >>= 1) {
        if (t < st) {
#pragma unroll
            for (int e = 0; e < EXP; ++e) fsum[t][e] += fsum[t + st][e];
        }
        __syncthreads();
    }
    if (t == 0) {
        float l = 0.f;
#pragma unroll
        for (int e = 0; e < EXP; ++e)
            l += (fsum[0][e] / (float)S_TOK) * ((float)tot[e] / (float)S_TOK);
        laux_out[0] = l * (float)EXP;
    }
}

// ---------------- Kernel 2b: gather + fp32->bf16 dispatch buffer ----------
// xd[slot][m] = bf16(x[slot_token[slot]][m]) or 0 for empty slots.
__global__ __launch_bounds__(256) void dispatch_cvt(
    const float* __restrict__ x, const int* __restrict__ slot_token,
    unsigned short* __restrict__ xd)
{
    const int slot = blockIdx.x, t = threadIdx.x;
    const int tok = slot_token[slot];
    unsigned short v[4];
    if (tok >= 0) {
        float4 f = *(const float4*)(x + (size_t)tok * MDIM + t * 4);
        v[0] = f2b(f.x); v[1] = f2b(f.y); v[2] = f2b(f.z); v[3] = f2b(f.w);
    } else {
        v[0] = v[1] = v[2] = v[3] = 0;
    }
    *(int2*)(xd + (size_t)slot * MDIM + t * 4) = *(const int2*)v;
}

// ---------------- Kernel 2c: transpose + cvt weights -----------------------
// src fp32 [e][R][C] -> dst bf16 [e][C][R].  64x64 tile per block.
__global__ __launch_bounds__(256) void transpose_cvt(
    const float* __restrict__ src, unsigned short* __restrict__ dst, int R, int C)
{
    __shared__ unsigned short Ls[64 * 72];
    const size_t eo = (size_t)blockIdx.z * R * C;
    src += eo; dst += eo;
    const int C0 = blockIdx.x * 64, R0 = blockIdx.y * 64;
    const int t = threadIdx.x;
    {
        const int r = t >> 2, c0 = (t & 3) * 16;
        const float* p = src + (size_t)(R0 + r) * C + C0 + c0;
        float f[16];
#pragma unroll
        for (int q = 0; q < 4; ++q) *(float4*)(f + q * 4) = ((const float4*)p)[q];
#pragma unroll
        for (int j = 0; j < 16; ++j) Ls[(c0 + j) * 72 + r] = f2b(f[j]);
    }
    __syncthreads();
    {
        const int c = t >> 2, m0 = (t & 3) * 16;
        int4 v0 = *(const int4*)&Ls[c * 72 + m0];
        int4 v1 = *(const int4*)&Ls[c * 72 + m0 + 8];
        int4* q = (int4*)(dst + (size_t)(C0 + c) * R + R0 + m0);
        q[0] = v0; q[1] = v1;
    }
}

// ---------------- Fast expert GEMM (both operands bf16 k-fast) -------------
// out[I=1024, N] = A[I, K] @ BT[N, K]^T per expert (blockIdx.z), bf16 MFMA.
// m97-structure: global_load_lds width-16 staging, double-buffered linear LDS,
// one barrier per K-step (T3 "minimum 2-phase").
// SCATTER: out row gi -> token slot_token[e*CAP+gi]; fp32 gate*val to d_out.
// !SCATTER: relu + bf16 store (row stride N).
template<int KSTEPS, int N, bool SCATTER>
__global__ __launch_bounds__(256) void ffn_gemm_fast(
    const unsigned short* __restrict__ Ab, const unsigned short* __restrict__ BT,
    void* __restrict__ Outv,
    const int* __restrict__ slot_token, const float* __restrict__ slot_gate)
{
    constexpr int K = KSTEPS * 32;
    const int e  = blockIdx.z;
    const int ib = blockIdx.y * 128;
    const int nb = blockIdx.x * 128;
    const int t  = threadIdx.x;

    // linear layout [128 rows][32 k] per buffer — REQUIRED by global_load_lds
    // (wave-uniform base + lane*16; padding would corrupt, m104/m173)
    __shared__ unsigned short As[2][128 * 32];
    __shared__ unsigned short Bs[2][128 * 32];

    const int lane = t & 63, wave = t >> 6;
    const int quad = lane >> 4, l15 = lane & 15;
    const int wr = wave >> 1, wc = wave & 1;

    // staging geometry: each wave fills 2 chunks (16 rows = 1 KB) of A and of B.
    // lane l -> row (chunk*16 + l/4), k-span (l&3)*8 .. +8  (16B per lane)
    const int c0    = wave * 2;          // first chunk owned by this wave (0..7 step 2)
    const int srow  = lane >> 2;         // 0..15 row within chunk
    const int kpart = (lane & 3) * 8;    // k element offset within 32-step

    const unsigned short* Ag = Ab + (size_t)(e * CAP + ib) * K + kpart;
    const unsigned short* Bg = BT + ((size_t)e * N + nb) * K + kpart;
    const size_t row0 = (size_t)(c0 * 16 + srow) * K;        // chunk c0 source row
    const size_t row1 = (size_t)(c0 * 16 + 16 + srow) * K;   // chunk c0+1 source row

    floatx4 acc[4][4];
#pragma unroll
    for (int r = 0; r < 4; ++r)
#pragma unroll
        for (int c = 0; c < 4; ++c)
            acc[r][c] = (floatx4){0.f, 0.f, 0.f, 0.f};

    // stage K-step kb into buffer buf (4 async 1KB wave-chunks)
    auto stage = [&](int buf, int kb) {
        const int k0 = kb * 32;
        gl2lds16(Ag + row0 + k0, &As[buf][(c0    ) * 512]);
        gl2lds16(Ag + row1 + k0, &As[buf][(c0 + 1) * 512]);
        gl2lds16(Bg + row0 + k0, &Bs[buf][(c0    ) * 512]);
        gl2lds16(Bg + row1 + k0, &Bs[buf][(c0 + 1) * 512]);
    };

    int cur = 0;
    stage(0, 0);
    __syncthreads();   // implicit vmcnt(0) drain -> buf0 ready

    for (int kb = 0; kb < KSTEPS; ++kb) {
        if (kb + 1 < KSTEPS) stage(cur ^ 1, kb + 1);   // async prefetch next tile

        short8 af[4], bfr[4];
#pragma unroll
        for (int r = 0; r < 4; ++r)
            af[r] = *(const short8*)&As[cur][(wr * 64 + r * 16 + l15) * 32 + quad * 8];
#pragma unroll
        for (int c = 0; c < 4; ++c)
            bfr[c] = *(const short8*)&Bs[cur][(wc * 64 + c * 16 + l15) * 32 + quad * 8];
#pragma unroll
        for (int r = 0; r < 4; ++r)
#pragma unroll
            for (int c = 0; c < 4; ++c)
                acc[r][c] = __builtin_amdgcn_mfma_f32_16x16x32_bf16(af[r], bfr[c], acc[r][c], 0, 0, 0);

        __syncthreads();   // reads of buf[cur] done; prefetch into buf[cur^1] drained
        cur ^= 1;
    }

    // epilogue: C/D layout col=lane&15, row=quad*4+reg
#pragma unroll
    for (int r = 0; r < 4; ++r) {
#pragma unroll
        for (int reg = 0; reg < 4; ++reg) {
            const int gi = ib + wr * 64 + r * 16 + quad * 4 + reg;
            if (SCATTER) {
                const int slot = e * CAP + gi;
                const int tok = slot_token[slot];
                if (tok >= 0) {
                    const float gsc = slot_gate[slot];
                    float* Out = (float*)Outv;
#pragma unroll
                    for (int c = 0; c < 4; ++c) {
                        const int gn = nb + wc * 64 + c * 16 + l15;
                        Out[(size_t)tok * N + gn] = gsc * acc[r][c][reg];
                    }
                }
            } else {
                unsigned short* Out = (unsigned short*)Outv;
#pragma unroll
                for (int c = 0; c < 4; ++c) {
                    const int gn = nb + wc * 64 + c * 16 + l15;
                    Out[((size_t)e * CAP + gi) * N + gn] = f2b(fmaxf(acc[r][c][reg], 0.f));
                }
            }
        }
    }
}

// ---------------- Fallback (R2, proven): fused-cvt GEMM --------------------
template<int KSTEPS, int N, bool GATHER, bool SCATTER>
__global__ __launch_bounds__(256) void ffn_gemm_slow(
    const void* __restrict__ Agv, const float* __restrict__ Bg,
    void* __restrict__ Outv,
    const int* __restrict__ slot_token, const float* __restrict__ slot_gate)
{
    constexpr int K = KSTEPS * 32;
    const int e  = blockIdx.z;
    const int ib = blockIdx.y * 128;
    const int nb = blockIdx.x * 128;
    const int t  = threadIdx.x;

    __shared__ unsigned short As[128 * 40];
    __shared__ unsigned short Bs[32 * 136];

    const float* B = Bg + (size_t)e * K * N;
    const int arow  = t >> 1;
    const int ahalf = t & 1;
    const float* ArowF = nullptr;
    const unsigned short* ArowH = nullptr;
    bool avalid = true;
    if (GATHER) {
        int tok = slot_token[e * CAP + ib + arow];
        avalid = (tok >= 0);
        ArowF = (const float*)Agv + (size_t)(avalid ? tok : 0) * K;
    } else {
        ArowH = (const unsigned short*)Agv + ((size_t)e * CAP + ib + arow) * K;
    }
    const int bk  = t >> 3;
    const int bn0 = (t & 7) * 16;
    const float* Bptr = B + (size_t)bk * N + nb + bn0;

    const int lane = t & 63, wave = t >> 6;
    const int quad = lane >> 4, l15 = lane & 15;
    const int wr = wave >> 1, wc = wave & 1;

    floatx4 acc[4][4];
#pragma unroll
    for (int r = 0; r < 4; ++r)
#pragma unroll
        for (int c = 0; c < 4; ++c)
            acc[r][c] = (floatx4){0.f, 0.f, 0.f, 0.f};

    for (int kb = 0; kb < KSTEPS; ++kb) {
        const int k0 = kb * 32;
        unsigned short av[16];
        if (GATHER) {
            if (avalid) {
                const float4* p = (const float4*)(ArowF + k0 + ahalf * 16);
                float4 f0 = p[0], f1 = p[1], f2 = p[2], f3 = p[3];
                const float fa[16] = {f0.x,f0.y,f0.z,f0.w, f1.x,f1.y,f1.z,f1.w,
                                      f2.x,f2.y,f2.z,f2.w, f3.x,f3.y,f3.z,f3.w};
#pragma unroll
                for (int j = 0; j < 16; ++j) av[j] = f2b(fa[j]);
            } else {
#pragma unroll
                for (int j = 0; j < 16; ++j) av[j] = 0;
            }
        } else {
            const int4* p = (const int4*)(ArowH + k0 + ahalf * 16);
            *(int4*)(av)     = p[0];
            *(int4*)(av + 8) = p[1];
        }
        unsigned short bv[16];
        {
            const float4* q = (const float4*)(Bptr + (size_t)k0 * N);
            float4 f0 = q[0], f1 = q[1], f2 = q[2], f3 = q[3];
            const float fb[16] = {f0.x,f0.y,f0.z,f0.w, f1.x,f1.y,f1.z,f1.w,
                                  f2.x,f2.y,f2.z,f2.w, f3.x,f3.y,f3.z,f3.w};
#pragma unroll
            for (int j = 0; j < 16; ++j) bv[j] = f2b(fb[j]);
        }

        *(int4*)&As[arow * 40 + ahalf * 16]     = *(int4*)(av);
        *(int4*)&As[arow * 40 + ahalf * 16 + 8] = *(int4*)(av + 8);
        *(int4*)&Bs[bk * 136 + bn0]             = *(int4*)(bv);
        *(int4*)&Bs[bk * 136 + bn0 + 8]         = *(int4*)(bv + 8);
        __syncthreads();

        short8 af[4];
#pragma unroll
        for (int r = 0; r < 4; ++r)
            af[r] = *(const short8*)&As[(wr * 64 + r * 16 + l15) * 40 + quad * 8];
        short8 bfr[4];
#pragma unroll
        for (int c = 0; c < 4; ++c) {
#pragma unroll
            for (int j = 0; j < 8; ++j)
                bfr[c][j] = (short)Bs[(quad * 8 + j) * 136 + wc * 64 + c * 16 + l15];
        }
#pragma unroll
        for (int r = 0; r < 4; ++r)
#pragma unroll
            for (int c = 0; c < 4; ++c)
                acc[r][c] = __builtin_amdgcn_mfma_f32_16x16x32_bf16(af[r], bfr[c], acc[r][c], 0, 0, 0);
        __syncthreads();
    }

#pragma unroll
    for (int r = 0; r < 4; ++r) {
#pragma unroll
        for (int reg = 0; reg < 4; ++reg) {
            const int gi = ib + wr * 64 + r * 16 + quad * 4 + reg;
            if (SCATTER) {
                const int slot = e * CAP + gi;
                const int tok = slot_token[slot];
                if (tok >= 0) {
                    const float gsc = slot_gate[slot];
                    float* Out = (float*)Outv;
#pragma unroll
                    for (int c = 0; c < 4; ++c) {
                        const int gn = nb + wc * 64 + c * 16 + l15;
                        Out[(size_t)tok * N + gn] = gsc * acc[r][c][reg];
                    }
                }
            } else {
                unsigned short* Out = (unsigned short*)Outv;
#pragma unroll
                for (int c = 0; c < 4; ++c) {
                    const int gn = nb + wc * 64 + c * 16 + l15;
                    Out[((size_t)e * CAP + gi) * N + gn] = f2b(fmaxf(acc[r][c][reg], 0.f));
                }
            }
        }
    }
}

extern "C" void kernel_launch(void* const* d_in, const int* in_sizes, int n_in,
                              void* d_out, int out_size, void* d_ws, size_t ws_size,
                              hipStream_t stream)
{
    const float* x  = (const float*)d_in[0];   // [8192,1024] fp32
    const float* wg = (const float*)d_in[1];   // [1024,8]    fp32
    const float* w1 = (const float*)d_in[2];   // [8,1024,4096] fp32
    const float* w2 = (const float*)d_in[3];   // [8,4096,1024] fp32
    float* out = (float*)d_out;                // 8388608 out + 1 l_aux, fp32

    char* ws = (char*)d_ws;
    float* gates8       = (float*)(ws);                 // 256 KB
    int*   token_expert = (int*)(ws + 262144);          // 32 KB
    int*   slot_token   = (int*)(ws + 294912);          // 32 KB
    float* slot_gate    = (float*)(ws + 327680);        // 32 KB

    hipMemsetAsync(d_out, 0, (size_t)out_size * 4, stream);
    gate_kernel<<<dim3(S_TOK / 4), dim3(256), 0, stream>>>(x, wg, gates8, token_expert);
    scan_kernel<<<dim3(1), dim3(256), 0, stream>>>(gates8, token_expert, slot_token, slot_gate,
                                                   out + (size_t)S_TOK * MDIM);

    const size_t FAST_NEED = 151355392ull;  // small(352K) + xd(16M) + h(64M) + W(64M)
    if (ws_size >= FAST_NEED) {
        unsigned short* xd = (unsigned short*)(ws + 360448);     // [8192,1024] bf16
        unsigned short* h  = (unsigned short*)(ws + 17137664);   // [8,1024,4096] bf16
        unsigned short* W  = (unsigned short*)(ws + 84246528);   // wT buffer, 64 MB

        dispatch_cvt<<<dim3(EXP * CAP), dim3(256), 0, stream>>>(x, slot_token, xd);
        // w1 [e][1024][4096] -> W [e][4096][1024]
        transpose_cvt<<<dim3(HDIM / 64, MDIM / 64, EXP), dim3(256), 0, stream>>>(w1, W, MDIM, HDIM);
        ffn_gemm_fast<32, HDIM, false><<<dim3(HDIM / 128, CAP / 128, EXP), dim3(256), 0, stream>>>(
            xd, W, h, slot_token, slot_gate);
        // w2 [e][4096][1024] -> W [e][1024][4096]
        transpose_cvt<<<dim3(MDIM / 64, HDIM / 64, EXP), dim3(256), 0, stream>>>(w2, W, HDIM, MDIM);
        ffn_gemm_fast<128, MDIM, true><<<dim3(MDIM / 128, CAP / 128, EXP), dim3(256), 0, stream>>>(
            h, W, out, slot_token, slot_gate);
    } else {
        unsigned short* h = (unsigned short*)(ws + 360448);      // [8,1024,4096] bf16
        ffn_gemm_slow<32, HDIM, true, false><<<dim3(HDIM / 128, CAP / 128, EXP), dim3(256), 0, stream>>>(
            x, w1, h, slot_token, slot_gate);
        ffn_gemm_slow<128, MDIM, false, true><<<dim3(MDIM / 128, CAP / 128, EXP), dim3(256), 0, stream>>>(
            h, w2, out, slot_token, slot_gate);
    }
}

// Round 2
// 568.919 us; speedup vs baseline: 1.1113x; 1.0938x over previous
//
#include <hip/hip_runtime.h>
#include <hip/hip_bf16.h>

// Problem constants (B=4,T=2048,M=1024,E=8,H=4096) — fp32 in/out
#define S_TOK 8192
#define MDIM  1024
#define EXP   8
#define HDIM  4096
#define CAP   1024   // s // E, capacity_factor = 1.0

typedef __attribute__((ext_vector_type(8))) short short8;
typedef __attribute__((ext_vector_type(4))) float floatx4;

#define BARRIER() asm volatile("s_barrier" ::: "memory")
#define WAITV6()  asm volatile("s_waitcnt vmcnt(6)" ::: "memory")
#define WAITV0()  asm volatile("s_waitcnt vmcnt(0)" ::: "memory")
#define SCHEDB()  __builtin_amdgcn_sched_barrier(0)

__device__ __forceinline__ unsigned short f2b(float f) {
    union { float f; unsigned int i; } v; v.f = f;
    unsigned int r = v.i + 0x7fffu + ((v.i >> 16) & 1u);  // RNE
    return (unsigned short)(r >> 16);
}

// async global->LDS, 16B per lane, wave-uniform LDS base (HW adds lane*16)
__device__ __forceinline__ void gl2lds16(const unsigned short* g, unsigned short* l) {
    __builtin_amdgcn_global_load_lds(
        (const __attribute__((address_space(1))) unsigned int*)g,
        (__attribute__((address_space(3))) unsigned int*)l,
        16, 0, 0);
}

// ---------------- Kernel 1: gating (pure fp32 — argmax must match np ref) ----
__global__ __launch_bounds__(256) void gate_kernel(
    const float* __restrict__ x, const float* __restrict__ wg,
    float* __restrict__ gates8, int* __restrict__ token_expert)
{
    const int wave = threadIdx.x >> 6, lane = threadIdx.x & 63;
    const int s = blockIdx.x * 4 + wave;

    const float* xr = x + (size_t)s * MDIM + lane * 16;
    float xv[16];
#pragma unroll
    for (int q = 0; q < 4; ++q) *(float4*)(xv + q * 4) = *(const float4*)(xr + q * 4);

    float acc[EXP];
#pragma unroll
    for (int e = 0; e < EXP; ++e) acc[e] = 0.f;
    const int m0 = lane * 16;
#pragma unroll
    for (int j = 0; j < 16; ++j) {
        const float xm = xv[j];
        const float* wr = wg + (size_t)(m0 + j) * EXP;
        float4 w0 = *(const float4*)(wr);
        float4 w1v = *(const float4*)(wr + 4);
        acc[0] += xm * w0.x; acc[1] += xm * w0.y; acc[2] += xm * w0.z; acc[3] += xm * w0.w;
        acc[4] += xm * w1v.x; acc[5] += xm * w1v.y; acc[6] += xm * w1v.z; acc[7] += xm * w1v.w;
    }
#pragma unroll
    for (int e = 0; e < EXP; ++e) {
#pragma unroll
        for (int off = 32; off > 0; off >>= 1)
            acc[e] += __shfl_down(acc[e], off);
    }
    if (lane == 0) {
        float mx = acc[0]; int idx = 0;
#pragma unroll
        for (int e = 1; e < EXP; ++e) if (acc[e] > mx) { mx = acc[e]; idx = e; }
        float g[EXP]; float sum = 0.f;
#pragma unroll
        for (int e = 0; e < EXP; ++e) { g[e] = expf(acc[e] - mx); sum += g[e]; }
        float inv = 1.f / sum;
#pragma unroll
        for (int e = 0; e < EXP; ++e) gates8[(size_t)s * EXP + e] = g[e] * inv;
        token_expert[s] = idx;
    }
}

// ---------------- Kernel 2: scan / slot assignment / l_aux ----------------
__global__ __launch_bounds__(256) void scan_kernel(
    const float* __restrict__ gates8, const int* __restrict__ token_expert,
    int* __restrict__ slot_token, float* __restrict__ slot_gate,
    float* __restrict__ laux_out)
{
    __shared__ int   cnt[256][EXP];
    __shared__ float fsum[256][EXP];
    __shared__ int   tot[EXP];
    const int t = threadIdx.x;

    for (int i = t; i < EXP * CAP; i += 256) slot_token[i] = -1;

    int local[EXP];
#pragma unroll
    for (int e = 0; e < EXP; ++e) local[e] = 0;
    const int s0 = t * 32;
    for (int j = 0; j < 32; ++j) local[token_expert[s0 + j]]++;
#pragma unroll
    for (int e = 0; e < EXP; ++e) cnt[t][e] = local[e];
    __syncthreads();

    if (t < EXP) {
        int run = 0;
        for (int i = 0; i < 256; ++i) { int v = cnt[i][t]; cnt[i][t] = run; run += v; }
        tot[t] = run;  // pre-drop count -> ce
    }
    __syncthreads();

    int off[EXP];
#pragma unroll
    for (int e = 0; e < EXP; ++e) off[e] = cnt[t][e];
    for (int j = 0; j < 32; ++j) {
        int s = s0 + j;
        int e = token_expert[s];
        int loc = off[e]++;
        if (loc < CAP) {
            int slot = e * CAP + loc;
            slot_token[slot] = s;
            slot_gate[slot]  = gates8[(size_t)s * EXP + e];
        }
    }

    float ms[EXP];
#pragma unroll
    for (int e = 0; e < EXP; ++e) ms[e] = 0.f;
    for (int j = 0; j < 32; ++j) {
        const float* g = gates8 + (size_t)(s0 + j) * EXP;
#pragma unroll
        for (int e = 0; e < EXP; ++e) ms[e] += g[e];
    }
#pragma unroll
    for (int e = 0; e < EXP; ++e) fsum[t][e] = ms[e];
    __syncthreads();
    for (int st = 128; st > 0; st >>= 1) {
        if (t < st) {
#pragma unroll
            for (int e = 0; e < EXP; ++e) fsum[t][e] += fsum[t + st][e];
        }
        __syncthreads();
    }
    if (t == 0) {
        float l = 0.f;
#pragma unroll
        for (int e = 0; e < EXP; ++e)
            l += (fsum[0][e] / (float)S_TOK) * ((float)tot[e] / (float)S_TOK);
        laux_out[0] = l * (float)EXP;
    }
}

// ---------------- Kernel 2b: gather + fp32->bf16 dispatch buffer ----------
__global__ __launch_bounds__(256) void dispatch_cvt(
    const float* __restrict__ x, const int* __restrict__ slot_token,
    unsigned short* __restrict__ xd)
{
    const int slot = blockIdx.x, t = threadIdx.x;
    const int tok = slot_token[slot];
    unsigned short v[4];
    if (tok >= 0) {
        float4 f = *(const float4*)(x + (size_t)tok * MDIM + t * 4);
        v[0] = f2b(f.x); v[1] = f2b(f.y); v[2] = f2b(f.z); v[3] = f2b(f.w);
    } else {
        v[0] = v[1] = v[2] = v[3] = 0;
    }
    *(int2*)(xd + (size_t)slot * MDIM + t * 4) = *(const int2*)v;
}

// ---------------- Kernel 2c: transpose + cvt weights -----------------------
// src fp32 [e][R][C] -> dst bf16 [e][C][R].  64x64 tile per block.
__global__ __launch_bounds__(256) void transpose_cvt(
    const float* __restrict__ src, unsigned short* __restrict__ dst, int R, int C)
{
    __shared__ unsigned short Ls[64 * 72];
    const size_t eo = (size_t)blockIdx.z * R * C;
    src += eo; dst += eo;
    const int C0 = blockIdx.x * 64, R0 = blockIdx.y * 64;
    const int t = threadIdx.x;
    {
        const int r = t >> 2, c0 = (t & 3) * 16;
        const float* p = src + (size_t)(R0 + r) * C + C0 + c0;
        float f[16];
#pragma unroll
        for (int q = 0; q < 4; ++q) *(float4*)(f + q * 4) = ((const float4*)p)[q];
#pragma unroll
        for (int j = 0; j < 16; ++j) Ls[(c0 + j) * 72 + r] = f2b(f[j]);
    }
    __syncthreads();
    {
        const int c = t >> 2, m0 = (t & 3) * 16;
        int4 v0 = *(const int4*)&Ls[c * 72 + m0];
        int4 v1 = *(const int4*)&Ls[c * 72 + m0 + 8];
        int4* q = (int4*)(dst + (size_t)(C0 + c) * R + R0 + m0);
        q[0] = v0; q[1] = v1;
    }
}

// ============ 8-phase-class pipelined expert GEMM (T1+T2+T3+T4+T5) =========
// out[CAP, N] = A[CAP, K] @ BT[N, K]^T per expert (blockIdx.z), bf16 MFMA.
// BM=256 BN=128 BK=64, 512 threads (8 waves as 2M x 4N), per-wave out 128x32.
// 3-deep LDS tile ring (144 KiB dynamic): tile t+2 staged into buffer freed
// by tile t-1 -> counted vmcnt(6) once per tile, never 0 in main loop.
// 4 phases/tile (C-quadrants), {ds_read || glds issue; barrier; setprio;
// 8 MFMA; setprio; barrier}. T2 swizzle: k-slot ^= row&7 via pre-swizzled
// global source (linear glds dest) + swizzled ds_read (rule 21).
template<int KT, int N, bool SCATTER>
__global__ __launch_bounds__(512, 2) void ffn_gemm_8p(
    const unsigned short* __restrict__ Ag, const unsigned short* __restrict__ BT,
    void* __restrict__ Outv,
    const int* __restrict__ slot_token, const float* __restrict__ slot_gate)
{
    constexpr int K   = KT * 64;
    constexpr int NBX = N / 128;
    constexpr int NWG = NBX * (CAP / 256);   // per-expert x-grid; NWG%8==0

    extern __shared__ __align__(16) unsigned short sm[];
    unsigned short* Abuf = sm;               // 3 * 16384 ushorts (96 KiB)
    unsigned short* Bbuf = sm + 3 * 16384;   // 3 *  8192 ushorts (48 KiB)

    const int e    = blockIdx.z;
    const int orig = blockIdx.x;
    // T1: bijective XCD swizzle (NWG divisible by 8)
    const int logical = (orig & 7) * (NWG >> 3) + (orig >> 3);
    const int nb = (logical % NBX) * 128;
    const int ib = (logical / NBX) * 256;

    const int tid  = threadIdx.x;
    const int lane = tid & 63, wave = tid >> 6;
    const int quad = lane >> 4, l15 = lane & 15;
    const int wm = wave >> 2, wn = wave & 3;

    // ---- staging addressing (per thread): chunk = 64 rows x 64 k = 8 KiB.
    // thread covers LDS bytes [tid*16, +16): row = tid/8, phys slot = tid&7.
    // T2: fetch logical slot = phys ^ (row&7) so swizzled data lands linearly.
    const int rr   = tid >> 3;                 // row within chunk (0..63)
    const int slot = (tid & 7) ^ (rr & 7);     // logical k-slot (8 bf16 each)
    const unsigned short* Asrc = Ag + (size_t)(e * CAP + ib + rr) * K + slot * 8;
    const unsigned short* Bsrc = BT + ((size_t)e * N + nb + rr) * K + slot * 8;

    auto stageA = [&](int buf, int t, int ca) {
        gl2lds16(Asrc + (size_t)ca * 64 * K + t * 64,
                 Abuf + buf * 16384 + ca * 4096 + wave * 512);
    };
    auto stageB = [&](int buf, int t, int cb) {
        gl2lds16(Bsrc + (size_t)cb * 64 * K + t * 64,
                 Bbuf + buf * 8192 + cb * 4096 + wave * 512);
    };

    // ---- fragment read addressing (swizzled): off = row*64 + ((ks*4+quad)^ (row&7))*8
    const int sx  = l15 & 7;                   // row&7 == l15&7 for all frag rows
    const int ko0 = ((0 + quad) ^ sx) * 8;     // ks = 0
    const int ko1 = ((4 + quad) ^ sx) * 8;     // ks = 1
    const int arow = wm * 128 + l15;           // + mh*64 + fm*16
    const int brow = wn * 32 + l15;            // + fn*16

    floatx4 acc[8][2];
#pragma unroll
    for (int i = 0; i < 8; ++i)
#pragma unroll
        for (int j = 0; j < 2; ++j)
            acc[i][j] = (floatx4){0.f, 0.f, 0.f, 0.f};

    // ---- prologue: stage tiles 0 and 1 fully (6 loads each per wave)
#pragma unroll
    for (int ca = 0; ca < 4; ++ca) stageA(0, 0, ca);
#pragma unroll
    for (int cb = 0; cb < 2; ++cb) stageB(0, 0, cb);
#pragma unroll
    for (int ca = 0; ca < 4; ++ca) stageA(1, 1, ca);
#pragma unroll
    for (int cb = 0; cb < 2; ++cb) stageB(1, 1, cb);
    WAITV6();   // tile 0's 6 loads done; tile 1's may be in flight
    BARRIER();

    int buf = 0;
    for (int t = 0; t < KT; ++t) {
        const int nbuf = (buf >= 1) ? buf - 1 : 2;   // (buf+2)%3
        const bool st  = (t + 2 < KT);

        // ---------- phase 0: read B(all) + A-half0; stage A0,A1; MFMA (m0,n0)
        short8 brg[2][2];
#pragma unroll
        for (int fn = 0; fn < 2; ++fn) {
            const int row = brow + fn * 16;
            brg[fn][0] = *(const short8*)&Bbuf[buf * 8192 + row * 64 + ko0];
            brg[fn][1] = *(const short8*)&Bbuf[buf * 8192 + row * 64 + ko1];
        }
        short8 aA[8];
#pragma unroll
        for (int fm = 0; fm < 4; ++fm) {
            const int row = arow + fm * 16;
            aA[fm * 2 + 0] = *(const short8*)&Abuf[buf * 16384 + row * 64 + ko0];
            aA[fm * 2 + 1] = *(const short8*)&Abuf[buf * 16384 + row * 64 + ko1];
        }
        if (st) { stageA(nbuf, t + 2, 0); stageA(nbuf, t + 2, 1); }
        BARRIER(); SCHEDB();
        __builtin_amdgcn_s_setprio(1);
#pragma unroll
        for (int fm = 0; fm < 4; ++fm) {
            acc[fm][0] = __builtin_amdgcn_mfma_f32_16x16x32_bf16(aA[fm*2+0], brg[0][0], acc[fm][0], 0, 0, 0);
            acc[fm][0] = __builtin_amdgcn_mfma_f32_16x16x32_bf16(aA[fm*2+1], brg[0][1], acc[fm][0], 0, 0, 0);
        }
        __builtin_amdgcn_s_setprio(0); SCHEDB(); BARRIER();

        // ---------- phase 1: read A-half1; stage A2,A3; MFMA (m0,n1)
        short8 aB[8];
#pragma unroll
        for (int fm = 0; fm < 4; ++fm) {
            const int row = arow + 64 + fm * 16;
            aB[fm * 2 + 0] = *(const short8*)&Abuf[buf * 16384 + row * 64 + ko0];
            aB[fm * 2 + 1] = *(const short8*)&Abuf[buf * 16384 + row * 64 + ko1];
        }
        if (st) { stageA(nbuf, t + 2, 2); stageA(nbuf, t + 2, 3); }
        BARRIER(); SCHEDB();
        __builtin_amdgcn_s_setprio(1);
#pragma unroll
        for (int fm = 0; fm < 4; ++fm) {
            acc[fm][1] = __builtin_amdgcn_mfma_f32_16x16x32_bf16(aA[fm*2+0], brg[1][0], acc[fm][1], 0, 0, 0);
            acc[fm][1] = __builtin_amdgcn_mfma_f32_16x16x32_bf16(aA[fm*2+1], brg[1][1], acc[fm][1], 0, 0, 0);
        }
        __builtin_amdgcn_s_setprio(0); SCHEDB(); BARRIER();

        // ---------- phase 2: stage B0; MFMA (m1,n0)
        if (st) stageB(nbuf, t + 2, 0);
        BARRIER(); SCHEDB();
        __builtin_amdgcn_s_setprio(1);
#pragma unroll
        for (int fm = 0; fm < 4; ++fm) {
            acc[4+fm][0] = __builtin_amdgcn_mfma_f32_16x16x32_bf16(aB[fm*2+0], brg[0][0], acc[4+fm][0], 0, 0, 0);
            acc[4+fm][0] = __builtin_amdgcn_mfma_f32_16x16x32_bf16(aB[fm*2+1], brg[0][1], acc[4+fm][0], 0, 0, 0);
        }
        __builtin_amdgcn_s_setprio(0); SCHEDB(); BARRIER();

        // ---------- phase 3: stage B1; MFMA (m1,n1); tile-granular vmcnt
        if (st) stageB(nbuf, t + 2, 1);
        BARRIER(); SCHEDB();
        __builtin_amdgcn_s_setprio(1);
#pragma unroll
        for (int fm = 0; fm < 4; ++fm) {
            acc[4+fm][1] = __builtin_amdgcn_mfma_f32_16x16x32_bf16(aB[fm*2+0], brg[1][0], acc[4+fm][1], 0, 0, 0);
            acc[4+fm][1] = __builtin_amdgcn_mfma_f32_16x16x32_bf16(aB[fm*2+1], brg[1][1], acc[4+fm][1], 0, 0, 0);
        }
        __builtin_amdgcn_s_setprio(0); SCHEDB();
        if (t + 1 < KT) {
            if (st) WAITV6(); else WAITV0();   // next tile's 6 loads complete
            BARRIER();
        }
        buf = (buf == 2) ? 0 : buf + 1;
    }

    // ---- epilogue: C/D layout col=lane&15, row=quad*4+reg
#pragma unroll
    for (int FM = 0; FM < 8; ++FM) {
        const int rowb = ib + wm * 128 + FM * 16 + quad * 4;
#pragma unroll
        for (int r = 0; r < 4; ++r) {
            const int gi = rowb + r;
            if (SCATTER) {
                const int slotI = e * CAP + gi;
                const int tok = slot_token[slotI];
                if (tok >= 0) {
                    const float gsc = slot_gate[slotI];
                    float* Out = (float*)Outv;
#pragma unroll
                    for (int fn = 0; fn < 2; ++fn) {
                        const int gn = nb + wn * 32 + fn * 16 + l15;
                        Out[(size_t)tok * N + gn] = gsc * acc[FM][fn][r];
                    }
                }
            } else {
                unsigned short* Out = (unsigned short*)Outv;
#pragma unroll
                for (int fn = 0; fn < 2; ++fn) {
                    const int gn = nb + wn * 32 + fn * 16 + l15;
                    Out[((size_t)e * CAP + gi) * N + gn] = f2b(fmaxf(acc[FM][fn][r], 0.f));
                }
            }
        }
    }
}

// ---------------- R1 fast GEMM (kept as fallback if dyn-LDS attr fails) ----
template<int KSTEPS, int N, bool SCATTER>
__global__ __launch_bounds__(256) void ffn_gemm_fast(
    const unsigned short* __restrict__ Ab, const unsigned short* __restrict__ BT,
    void* __restrict__ Outv,
    const int* __restrict__ slot_token, const float* __restrict__ slot_gate)
{
    constexpr int K = KSTEPS * 32;
    const int e  = blockIdx.z;
    const int ib = blockIdx.y * 128;
    const int nb = blockIdx.x * 128;
    const int t  = threadIdx.x;

    __shared__ unsigned short As[2][128 * 32];
    __shared__ unsigned short Bs[2][128 * 32];

    const int lane = t & 63, wave = t >> 6;
    const int quad = lane >> 4, l15 = lane & 15;
    const int wr = wave >> 1, wc = wave & 1;

    const int c0    = wave * 2;
    const int srow  = lane >> 2;
    const int kpart = (lane & 3) * 8;

    const unsigned short* Ag = Ab + (size_t)(e * CAP + ib) * K + kpart;
    const unsigned short* Bg = BT + ((size_t)e * N + nb) * K + kpart;
    const size_t row0 = (size_t)(c0 * 16 + srow) * K;
    const size_t row1 = (size_t)(c0 * 16 + 16 + srow) * K;

    floatx4 acc[4][4];
#pragma unroll
    for (int r = 0; r < 4; ++r)
#pragma unroll
        for (int c = 0; c < 4; ++c)
            acc[r][c] = (floatx4){0.f, 0.f, 0.f, 0.f};

    auto stage = [&](int buf, int kb) {
        const int k0 = kb * 32;
        gl2lds16(Ag + row0 + k0, &As[buf][(c0    ) * 512]);
        gl2lds16(Ag + row1 + k0, &As[buf][(c0 + 1) * 512]);
        gl2lds16(Bg + row0 + k0, &Bs[buf][(c0    ) * 512]);
        gl2lds16(Bg + row1 + k0, &Bs[buf][(c0 + 1) * 512]);
    };

    int cur = 0;
    stage(0, 0);
    __syncthreads();

    for (int kb = 0; kb < KSTEPS; ++kb) {
        if (kb + 1 < KSTEPS) stage(cur ^ 1, kb + 1);

        short8 af[4], bfr[4];
#pragma unroll
        for (int r = 0; r < 4; ++r)
            af[r] = *(const short8*)&As[cur][(wr * 64 + r * 16 + l15) * 32 + quad * 8];
#pragma unroll
        for (int c = 0; c < 4; ++c)
            bfr[c] = *(const short8*)&Bs[cur][(wc * 64 + c * 16 + l15) * 32 + quad * 8];
#pragma unroll
        for (int r = 0; r < 4; ++r)
#pragma unroll
            for (int c = 0; c < 4; ++c)
                acc[r][c] = __builtin_amdgcn_mfma_f32_16x16x32_bf16(af[r], bfr[c], acc[r][c], 0, 0, 0);

        __syncthreads();
        cur ^= 1;
    }

#pragma unroll
    for (int r = 0; r < 4; ++r) {
#pragma unroll
        for (int reg = 0; reg < 4; ++reg) {
            const int gi = ib + wr * 64 + r * 16 + quad * 4 + reg;
            if (SCATTER) {
                const int slot = e * CAP + gi;
                const int tok = slot_token[slot];
                if (tok >= 0) {
                    const float gsc = slot_gate[slot];
                    float* Out = (float*)Outv;
#pragma unroll
                    for (int c = 0; c < 4; ++c) {
                        const int gn = nb + wc * 64 + c * 16 + l15;
                        Out[(size_t)tok * N + gn] = gsc * acc[r][c][reg];
                    }
                }
            } else {
                unsigned short* Out = (unsigned short*)Outv;
#pragma unroll
                for (int c = 0; c < 4; ++c) {
                    const int gn = nb + wc * 64 + c * 16 + l15;
                    Out[((size_t)e * CAP + gi) * N + gn] = f2b(fmaxf(acc[r][c][reg], 0.f));
                }
            }
        }
    }
}

// ---------------- Fallback (R2, proven): fused-cvt GEMM --------------------
template<int KSTEPS, int N, bool GATHER, bool SCATTER>
__global__ __launch_bounds__(256) void ffn_gemm_slow(
    const void* __restrict__ Agv, const float* __restrict__ Bg,
    void* __restrict__ Outv,
    const int* __restrict__ slot_token, const float* __restrict__ slot_gate)
{
    constexpr int K = KSTEPS * 32;
    const int e  = blockIdx.z;
    const int ib = blockIdx.y * 128;
    const int nb = blockIdx.x * 128;
    const int t  = threadIdx.x;

    __shared__ unsigned short As[128 * 40];
    __shared__ unsigned short Bs[32 * 136];

    const float* B = Bg + (size_t)e * K * N;
    const int arow  = t >> 1;
    const int ahalf = t & 1;
    const float* ArowF = nullptr;
    const unsigned short* ArowH = nullptr;
    bool avalid = true;
    if (GATHER) {
        int tok = slot_token[e * CAP + ib + arow];
        avalid = (tok >= 0);
        ArowF = (const float*)Agv + (size_t)(avalid ? tok : 0) * K;
    } else {
        ArowH = (const unsigned short*)Agv + ((size_t)e * CAP + ib + arow) * K;
    }
    const int bk  = t >> 3;
    const int bn0 = (t & 7) * 16;
    const float* Bptr = B + (size_t)bk * N + nb + bn0;

    const int lane = t & 63, wave = t >> 6;
    const int quad = lane >> 4, l15 = lane & 15;
    const int wr = wave >> 1, wc = wave & 1;

    floatx4 acc[4][4];
#pragma unroll
    for (int r = 0; r < 4; ++r)
#pragma unroll
        for (int c = 0; c < 4; ++c)
            acc[r][c] = (floatx4){0.f, 0.f, 0.f, 0.f};

    for (int kb = 0; kb < KSTEPS; ++kb) {
        const int k0 = kb * 32;
        unsigned short av[16];
        if (GATHER) {
            if (avalid) {
                const float4* p = (const float4*)(ArowF + k0 + ahalf * 16);
                float4 f0 = p[0], f1 = p[1], f2 = p[2], f3 = p[3];
                const float fa[16] = {f0.x,f0.y,f0.z,f0.w, f1.x,f1.y,f1.z,f1.w,
                                      f2.x,f2.y,f2.z,f2.w, f3.x,f3.y,f3.z,f3.w};
#pragma unroll
                for (int j = 0; j < 16; ++j) av[j] = f2b(fa[j]);
            } else {
#pragma unroll
                for (int j = 0; j < 16; ++j) av[j] = 0;
            }
        } else {
            const int4* p = (const int4*)(ArowH + k0 + ahalf * 16);
            *(int4*)(av)     = p[0];
            *(int4*)(av + 8) = p[1];
        }
        unsigned short bv[16];
        {
            const float4* q = (const float4*)(Bptr + (size_t)k0 * N);
            float4 f0 = q[0], f1 = q[1], f2 = q[2], f3 = q[3];
            const float fb[16] = {f0.x,f0.y,f0.z,f0.w, f1.x,f1.y,f1.z,f1.w,
                                  f2.x,f2.y,f2.z,f2.w, f3.x,f3.y,f3.z,f3.w};
#pragma unroll
            for (int j = 0; j < 16; ++j) bv[j] = f2b(fb[j]);
        }

        *(int4*)&As[arow * 40 + ahalf * 16]     = *(int4*)(av);
        *(int4*)&As[arow * 40 + ahalf * 16 + 8] = *(int4*)(av + 8);
        *(int4*)&Bs[bk * 136 + bn0]             = *(int4*)(bv);
        *(int4*)&Bs[bk * 136 + bn0 + 8]         = *(int4*)(bv + 8);
        __syncthreads();

        short8 af[4];
#pragma unroll
        for (int r = 0; r < 4; ++r)
            af[r] = *(const short8*)&As[(wr * 64 + r * 16 + l15) * 40 + quad * 8];
        short8 bfr[4];
#pragma unroll
        for (int c = 0; c < 4; ++c) {
#pragma unroll
            for (int j = 0; j < 8; ++j)
                bfr[c][j] = (short)Bs[(quad * 8 + j) * 136 + wc * 64 + c * 16 + l15];
        }
#pragma unroll
        for (int r = 0; r < 4; ++r)
#pragma unroll
            for (int c = 0; c < 4; ++c)
                acc[r][c] = __builtin_amdgcn_mfma_f32_16x16x32_bf16(af[r], bfr[c], acc[r][c], 0, 0, 0);
        __syncthreads();
    }

#pragma unroll
    for (int r = 0; r < 4; ++r) {
#pragma unroll
        for (int reg = 0; reg < 4; ++reg) {
            const int gi = ib + wr * 64 + r * 16 + quad * 4 + reg;
            if (SCATTER) {
                const int slot = e * CAP + gi;
                const int tok = slot_token[slot];
                if (tok >= 0) {
                    const float gsc = slot_gate[slot];
                    float* Out = (float*)Outv;
#pragma unroll
                    for (int c = 0; c < 4; ++c) {
                        const int gn = nb + wc * 64 + c * 16 + l15;
                        Out[(size_t)tok * N + gn] = gsc * acc[r][c][reg];
                    }
                }
            } else {
                unsigned short* Out = (unsigned short*)Outv;
#pragma unroll
                for (int c = 0; c < 4; ++c) {
                    const int gn = nb + wc * 64 + c * 16 + l15;
                    Out[((size_t)e * CAP + gi) * N + gn] = f2b(fmaxf(acc[r][c][reg], 0.f));
                }
            }
        }
    }
}

extern "C" void kernel_launch(void* const* d_in, const int* in_sizes, int n_in,
                              void* d_out, int out_size, void* d_ws, size_t ws_size,
                              hipStream_t stream)
{
    const float* x  = (const float*)d_in[0];   // [8192,1024] fp32
    const float* wg = (const float*)d_in[1];   // [1024,8]    fp32
    const float* w1 = (const float*)d_in[2];   // [8,1024,4096] fp32
    const float* w2 = (const float*)d_in[3];   // [8,4096,1024] fp32
    float* out = (float*)d_out;                // 8388608 out + 1 l_aux, fp32

    char* ws = (char*)d_ws;
    float* gates8       = (float*)(ws);                 // 256 KB
    int*   token_expert = (int*)(ws + 262144);          // 32 KB
    int*   slot_token   = (int*)(ws + 294912);          // 32 KB
    float* slot_gate    = (float*)(ws + 327680);        // 32 KB

    hipMemsetAsync(d_out, 0, (size_t)out_size * 4, stream);
    gate_kernel<<<dim3(S_TOK / 4), dim3(256), 0, stream>>>(x, wg, gates8, token_expert);
    scan_kernel<<<dim3(1), dim3(256), 0, stream>>>(gates8, token_expert, slot_token, slot_gate,
                                                   out + (size_t)S_TOK * MDIM);

    const size_t FAST_NEED = 151355392ull;  // small(352K) + xd(16M) + h(64M) + W(64M)
    if (ws_size >= FAST_NEED) {
        unsigned short* xd = (unsigned short*)(ws + 360448);     // [8192,1024] bf16
        unsigned short* h  = (unsigned short*)(ws + 17137664);   // [8,1024,4096] bf16
        unsigned short* W  = (unsigned short*)(ws + 84246528);   // wT buffer, 64 MB

        // one-time: allow 144 KiB dynamic LDS for the pipelined GEMM
        static bool tried = false, ok8 = false;
        if (!tried) {
            tried = true;
            ok8 = (hipFuncSetAttribute((const void*)ffn_gemm_8p<16, HDIM, false>,
                       hipFuncAttributeMaxDynamicSharedMemorySize, 147456) == hipSuccess)
               && (hipFuncSetAttribute((const void*)ffn_gemm_8p<64, MDIM, true>,
                       hipFuncAttributeMaxDynamicSharedMemorySize, 147456) == hipSuccess);
        }

        dispatch_cvt<<<dim3(EXP * CAP), dim3(256), 0, stream>>>(x, slot_token, xd);
        // w1 [e][1024][4096] -> W [e][4096][1024]
        transpose_cvt<<<dim3(HDIM / 64, MDIM / 64, EXP), dim3(256), 0, stream>>>(w1, W, MDIM, HDIM);
        if (ok8) {
            ffn_gemm_8p<16, HDIM, false><<<dim3((HDIM/128) * (CAP/256), 1, EXP), dim3(512), 147456, stream>>>(
                xd, W, h, slot_token, slot_gate);
        } else {
            ffn_gemm_fast<32, HDIM, false><<<dim3(HDIM / 128, CAP / 128, EXP), dim3(256), 0, stream>>>(
                xd, W, h, slot_token, slot_gate);
        }
        // w2 [e][4096][1024] -> W [e][1024][4096]
        transpose_cvt<<<dim3(MDIM / 64, HDIM / 64, EXP), dim3(256), 0, stream>>>(w2, W, HDIM, MDIM);
        if (ok8) {
            ffn_gemm_8p<64, MDIM, true><<<dim3((MDIM/128) * (CAP/256), 1, EXP), dim3(512), 147456, stream>>>(
                h, W, out, slot_token, slot_gate);
        } else {
            ffn_gemm_fast<128, MDIM, true><<<dim3(MDIM / 128, CAP / 128, EXP), dim3(256), 0, stream>>>(
                h, W, out, slot_token, slot_gate);
        }
    } else {
        unsigned short* h = (unsigned short*)(ws + 360448);      // [8,1024,4096] bf16
        ffn_gemm_slow<32, HDIM, true, false><<<dim3(HDIM / 128, CAP / 128, EXP), dim3(256), 0, stream>>>(
            x, w1, h, slot_token, slot_gate);
        ffn_gemm_slow<128, MDIM, false, true><<<dim3(MDIM / 128, CAP / 128, EXP), dim3(256), 0, stream>>>(
            h, w2, out, slot_token, slot_gate);
    }
}

// Round 3
// 549.429 us; speedup vs baseline: 1.1508x; 1.0355x over previous
//
#include <hip/hip_runtime.h>
#include <hip/hip_bf16.h>

// Problem constants (B=4,T=2048,M=1024,E=8,H=4096) — fp32 in/out
#define S_TOK 8192
#define MDIM  1024
#define EXP   8
#define HDIM  4096
#define CAP   1024   // s // E, capacity_factor = 1.0

typedef __attribute__((ext_vector_type(8))) short short8;
typedef __attribute__((ext_vector_type(4))) float floatx4;

#define BARRIER() asm volatile("s_barrier" ::: "memory")
#define WAITV6()  asm volatile("s_waitcnt vmcnt(6)" ::: "memory")
#define WAITV0()  asm volatile("s_waitcnt vmcnt(0)" ::: "memory")
#define SCHEDB()  __builtin_amdgcn_sched_barrier(0)

__device__ __forceinline__ unsigned short f2b(float f) {
    union { float f; unsigned int i; } v; v.f = f;
    unsigned int r = v.i + 0x7fffu + ((v.i >> 16) & 1u);  // RNE
    return (unsigned short)(r >> 16);
}

// async global->LDS, 16B per lane, wave-uniform LDS base (HW adds lane*16)
__device__ __forceinline__ void gl2lds16(const unsigned short* g, unsigned short* l) {
    __builtin_amdgcn_global_load_lds(
        (const __attribute__((address_space(1))) unsigned int*)g,
        (__attribute__((address_space(3))) unsigned int*)l,
        16, 0, 0);
}

// ---------------- Kernel 1: gating (+ bf16 cast of x) ----------------------
// argmax/softmax in pure fp32 (must match np ref); also writes xb16 = bf16(x)
__global__ __launch_bounds__(256) void gate_kernel(
    const float* __restrict__ x, const float* __restrict__ wg,
    float* __restrict__ gates8, int* __restrict__ token_expert,
    unsigned short* __restrict__ xb16)
{
    const int wave = threadIdx.x >> 6, lane = threadIdx.x & 63;
    const int s = blockIdx.x * 4 + wave;

    const float* xr = x + (size_t)s * MDIM + lane * 16;
    float xv[16];
#pragma unroll
    for (int q = 0; q < 4; ++q) *(float4*)(xv + q * 4) = *(const float4*)(xr + q * 4);

    if (xb16) {
        unsigned short bv[16];
#pragma unroll
        for (int j = 0; j < 16; ++j) bv[j] = f2b(xv[j]);
        int4* dst = (int4*)(xb16 + (size_t)s * MDIM + lane * 16);
        dst[0] = ((const int4*)bv)[0];
        dst[1] = ((const int4*)bv)[1];
    }

    float acc[EXP];
#pragma unroll
    for (int e = 0; e < EXP; ++e) acc[e] = 0.f;
    const int m0 = lane * 16;
#pragma unroll
    for (int j = 0; j < 16; ++j) {
        const float xm = xv[j];
        const float* wr = wg + (size_t)(m0 + j) * EXP;
        float4 w0 = *(const float4*)(wr);
        float4 w1v = *(const float4*)(wr + 4);
        acc[0] += xm * w0.x; acc[1] += xm * w0.y; acc[2] += xm * w0.z; acc[3] += xm * w0.w;
        acc[4] += xm * w1v.x; acc[5] += xm * w1v.y; acc[6] += xm * w1v.z; acc[7] += xm * w1v.w;
    }
#pragma unroll
    for (int e = 0; e < EXP; ++e) {
#pragma unroll
        for (int off = 32; off > 0; off >>= 1)
            acc[e] += __shfl_down(acc[e], off);
    }
    if (lane == 0) {
        float mx = acc[0]; int idx = 0;
#pragma unroll
        for (int e = 1; e < EXP; ++e) if (acc[e] > mx) { mx = acc[e]; idx = e; }
        float g[EXP]; float sum = 0.f;
#pragma unroll
        for (int e = 0; e < EXP; ++e) { g[e] = expf(acc[e] - mx); sum += g[e]; }
        float inv = 1.f / sum;
#pragma unroll
        for (int e = 0; e < EXP; ++e) gates8[(size_t)s * EXP + e] = g[e] * inv;
        token_expert[s] = idx;
    }
}

// ---------------- transpose tile helper (64x64, fp32 -> bf16 ^T) ----------
__device__ __forceinline__ void transpose_tile(
    const float* __restrict__ src, unsigned short* __restrict__ dst,
    int R, int C, int R0, int C0, unsigned short* Ls)
{
    const int t = threadIdx.x;
    {
        const int r = t >> 2, c0 = (t & 3) * 16;
        const float* p = src + (size_t)(R0 + r) * C + C0 + c0;
        float f[16];
#pragma unroll
        for (int q = 0; q < 4; ++q) *(float4*)(f + q * 4) = ((const float4*)p)[q];
#pragma unroll
        for (int j = 0; j < 16; ++j) Ls[(c0 + j) * 72 + r] = f2b(f[j]);
    }
    __syncthreads();
    {
        const int c = t >> 2, m0 = (t & 3) * 16;
        int4 v0 = *(const int4*)&Ls[c * 72 + m0];
        int4 v1 = *(const int4*)&Ls[c * 72 + m0 + 8];
        int4* q = (int4*)(dst + (size_t)(C0 + c) * R + R0 + m0);
        q[0] = v0; q[1] = v1;
    }
}

// ---------------- mega_prep: scan (block 0) + out-zero + weight transposes -
// block 0          : scan / slot assignment / l_aux (parallel prefix)
// blocks 1..2048   : zero out[8192][1024] fp32
// blocks 2049..+8192-1   : w1 [e][1024][4096] -> W1T [e][4096][1024]
// blocks +8192..+16384-1 : w2 [e][4096][1024] -> W2T [e][1024][4096] (wide ws)
__global__ __launch_bounds__(256) void mega_prep(
    const float* __restrict__ gates8, const int* __restrict__ token_expert,
    int* __restrict__ slot_token, float* __restrict__ slot_gate,
    float* __restrict__ laux_out,
    const float* __restrict__ w1, const float* __restrict__ w2,
    unsigned short* __restrict__ W1T, unsigned short* __restrict__ W2T,
    float* __restrict__ outz)
{
    __shared__ int            cntS[256 * EXP];
    __shared__ float          fsumS[256 * EXP];
    __shared__ unsigned short Ls[64 * 72];

    const int b = blockIdx.x;
    const int t = threadIdx.x;

    if (b == 0) {
        // ---------------- scan ----------------
        for (int i = t; i < EXP * CAP; i += 256) slot_token[i] = -1;

        int local[EXP];
#pragma unroll
        for (int e = 0; e < EXP; ++e) local[e] = 0;
        const int s0 = t * 32;
        for (int j = 0; j < 32; ++j) local[token_expert[s0 + j]]++;

        int incl[EXP];
#pragma unroll
        for (int e = 0; e < EXP; ++e) { incl[e] = local[e]; cntS[t * EXP + e] = incl[e]; }
        __syncthreads();
        // Hillis-Steele inclusive scan over 256 entries (8 steps)
        for (int d = 1; d < 256; d <<= 1) {
            int add[EXP];
            if (t >= d) {
#pragma unroll
                for (int e = 0; e < EXP; ++e) add[e] = cntS[(t - d) * EXP + e];
            }
            __syncthreads();
            if (t >= d) {
#pragma unroll
                for (int e = 0; e < EXP; ++e) { incl[e] += add[e]; cntS[t * EXP + e] = incl[e]; }
            }
            __syncthreads();
        }

        int off[EXP];
#pragma unroll
        for (int e = 0; e < EXP; ++e) off[e] = incl[e] - local[e];
        for (int j = 0; j < 32; ++j) {
            int s = s0 + j;
            int e = token_expert[s];
            int loc = off[e]++;
            if (loc < CAP) {
                int slot = e * CAP + loc;
                slot_token[slot] = s;
                slot_gate[slot]  = gates8[(size_t)s * EXP + e];
            }
        }

        float ms[EXP];
#pragma unroll
        for (int e = 0; e < EXP; ++e) ms[e] = 0.f;
        for (int j = 0; j < 32; ++j) {
            const float* g = gates8 + (size_t)(s0 + j) * EXP;
#pragma unroll
            for (int e = 0; e < EXP; ++e) ms[e] += g[e];
        }
#pragma unroll
        for (int e = 0; e < EXP; ++e) fsumS[t * EXP + e] = ms[e];
        __syncthreads();
        for (int st = 128; st > 0; st >>= 1) {
            if (t < st) {
#pragma unroll
                for (int e = 0; e < EXP; ++e) fsumS[t * EXP + e] += fsumS[(t + st) * EXP + e];
            }
            __syncthreads();
        }
        if (t == 0) {
            float l = 0.f;
#pragma unroll
            for (int e = 0; e < EXP; ++e)
                l += (fsumS[e] / (float)S_TOK) * ((float)cntS[255 * EXP + e] / (float)S_TOK);
            laux_out[0] = l * (float)EXP;
        }
        return;
    }

    if (b <= 2048) {
        // ---------------- zero out ----------------
        float4* p = (float4*)(outz + (size_t)(b - 1) * 4096 + t * 16);
        const float4 z = {0.f, 0.f, 0.f, 0.f};
        p[0] = z; p[1] = z; p[2] = z; p[3] = z;
        return;
    }

    int i = b - 2049;
    if (i < 8192) {
        // ---------------- w1 transpose: R=1024, C=4096 ----------------
        const int e = i >> 10, rem = i & 1023;
        const int bx = rem & 63, by = rem >> 6;
        transpose_tile(w1 + (size_t)e * MDIM * HDIM, W1T + (size_t)e * MDIM * HDIM,
                       MDIM, HDIM, by * 64, bx * 64, Ls);
        return;
    }
    i -= 8192;
    {
        // ---------------- w2 transpose: R=4096, C=1024 ----------------
        const int e = i >> 10, rem = i & 1023;
        const int bx = rem & 15, by = rem >> 4;
        transpose_tile(w2 + (size_t)e * MDIM * HDIM, W2T + (size_t)e * MDIM * HDIM,
                       HDIM, MDIM, by * 64, bx * 64, Ls);
    }
}

// ---------------- standalone transpose (narrow-ws path, between GEMMs) -----
__global__ __launch_bounds__(256) void transpose_cvt(
    const float* __restrict__ src, unsigned short* __restrict__ dst, int R, int C)
{
    __shared__ unsigned short Ls[64 * 72];
    const size_t eo = (size_t)blockIdx.z * R * C;
    transpose_tile(src + eo, dst + eo, R, C, blockIdx.y * 64, blockIdx.x * 64, Ls);
}

// ============ 8-phase-class pipelined expert GEMM (T1+T2+T3+T4+T5) =========
// out[CAP, N] = A[CAP, K] @ BT[N, K]^T per expert (blockIdx.z), bf16 MFMA.
// BM=256 BN=128 BK=64, 512 threads (8 waves as 2M x 4N), per-wave out 128x32.
// 3-deep LDS tile ring (144 KiB dynamic): tile t+2 staged into buffer freed
// by tile t-1 -> counted vmcnt(6) once per tile, never 0 in main loop.
// GATHER: A row r sourced from Ag + slot_token[e*CAP+r]*K (xb16); empty
// slots read token 0 (finite garbage, discarded at GEMM2's scatter).
template<int KT, int N, bool SCATTER, bool GATHER>
__global__ __launch_bounds__(512, 2) void ffn_gemm_8p(
    const unsigned short* __restrict__ Ag, const unsigned short* __restrict__ BT,
    void* __restrict__ Outv,
    const int* __restrict__ slot_token, const float* __restrict__ slot_gate)
{
    constexpr int K   = KT * 64;
    constexpr int NBX = N / 128;
    constexpr int NWG = NBX * (CAP / 256);   // per-expert x-grid; NWG%8==0

    extern __shared__ __align__(16) unsigned short sm[];
    unsigned short* Abuf = sm;               // 3 * 16384 ushorts (96 KiB)
    unsigned short* Bbuf = sm + 3 * 16384;   // 3 *  8192 ushorts (48 KiB)

    const int e    = blockIdx.z;
    const int orig = blockIdx.x;
    // T1: bijective XCD swizzle (NWG divisible by 8)
    const int logical = (orig & 7) * (NWG >> 3) + (orig >> 3);
    const int nb = (logical % NBX) * 128;
    const int ib = (logical / NBX) * 256;

    const int tid  = threadIdx.x;
    const int lane = tid & 63, wave = tid >> 6;
    const int quad = lane >> 4, l15 = lane & 15;
    const int wm = wave >> 2, wn = wave & 3;

    // ---- staging addressing (per thread): chunk = 64 rows x 64 k = 8 KiB.
    // thread covers LDS bytes [tid*16, +16): row = tid/8, phys slot = tid&7.
    // T2: fetch logical slot = phys ^ (row&7) so swizzled data lands linearly.
    const int rr   = tid >> 3;                 // row within chunk (0..63)
    const int slot = (tid & 7) ^ (rr & 7);     // logical k-slot (8 bf16 each)

    const unsigned short* sA0;
    const unsigned short* sA1;
    const unsigned short* sA2;
    const unsigned short* sA3;
    if (GATHER) {
        const int base = e * CAP + ib + rr;
        int t0 = slot_token[base];
        int t1 = slot_token[base + 64];
        int t2 = slot_token[base + 128];
        int t3 = slot_token[base + 192];
        sA0 = Ag + (size_t)(t0 < 0 ? 0 : t0) * K + slot * 8;
        sA1 = Ag + (size_t)(t1 < 0 ? 0 : t1) * K + slot * 8;
        sA2 = Ag + (size_t)(t2 < 0 ? 0 : t2) * K + slot * 8;
        sA3 = Ag + (size_t)(t3 < 0 ? 0 : t3) * K + slot * 8;
    } else {
        sA0 = Ag + (size_t)(e * CAP + ib + rr) * K + slot * 8;
        sA1 = sA0 + (size_t)64 * K;
        sA2 = sA0 + (size_t)128 * K;
        sA3 = sA0 + (size_t)192 * K;
    }
    const unsigned short* Bsrc = BT + ((size_t)e * N + nb + rr) * K + slot * 8;

    auto stageA = [&](int buf, int t, const unsigned short* s, int ca) {
        gl2lds16(s + t * 64, Abuf + buf * 16384 + ca * 4096 + wave * 512);
    };
    auto stageB = [&](int buf, int t, int cb) {
        gl2lds16(Bsrc + (size_t)cb * 64 * K + t * 64,
                 Bbuf + buf * 8192 + cb * 4096 + wave * 512);
    };

    // ---- fragment read addressing (swizzled): off = row*64 + ((ks*4+quad)^(row&7))*8
    const int sx  = l15 & 7;                   // row&7 == l15&7 for all frag rows
    const int ko0 = ((0 + quad) ^ sx) * 8;     // ks = 0
    const int ko1 = ((4 + quad) ^ sx) * 8;     // ks = 1
    const int arow = wm * 128 + l15;           // + mh*64 + fm*16
    const int brow = wn * 32 + l15;            // + fn*16

    floatx4 acc[8][2];
#pragma unroll
    for (int i = 0; i < 8; ++i)
#pragma unroll
        for (int j = 0; j < 2; ++j)
            acc[i][j] = (floatx4){0.f, 0.f, 0.f, 0.f};

    // ---- prologue: stage tiles 0 and 1 fully (6 loads each per wave)
    stageA(0, 0, sA0, 0); stageA(0, 0, sA1, 1); stageA(0, 0, sA2, 2); stageA(0, 0, sA3, 3);
    stageB(0, 0, 0); stageB(0, 0, 1);
    stageA(1, 1, sA0, 0); stageA(1, 1, sA1, 1); stageA(1, 1, sA2, 2); stageA(1, 1, sA3, 3);
    stageB(1, 1, 0); stageB(1, 1, 1);
    WAITV6();   // tile 0's 6 loads done; tile 1's may be in flight
    BARRIER();

    int buf = 0;
    for (int t = 0; t < KT; ++t) {
        const int nbuf = (buf >= 1) ? buf - 1 : 2;   // (buf+2)%3
        const bool st  = (t + 2 < KT);

        // ---------- phase 0: read B(all) + A-half0; stage A0,A1; MFMA (m0,n0)
        short8 brg[2][2];
#pragma unroll
        for (int fn = 0; fn < 2; ++fn) {
            const int row = brow + fn * 16;
            brg[fn][0] = *(const short8*)&Bbuf[buf * 8192 + row * 64 + ko0];
            brg[fn][1] = *(const short8*)&Bbuf[buf * 8192 + row * 64 + ko1];
        }
        short8 aA[8];
#pragma unroll
        for (int fm = 0; fm < 4; ++fm) {
            const int row = arow + fm * 16;
            aA[fm * 2 + 0] = *(const short8*)&Abuf[buf * 16384 + row * 64 + ko0];
            aA[fm * 2 + 1] = *(const short8*)&Abuf[buf * 16384 + row * 64 + ko1];
        }
        if (st) { stageA(nbuf, t + 2, sA0, 0); stageA(nbuf, t + 2, sA1, 1); }
        BARRIER(); SCHEDB();
        __builtin_amdgcn_s_setprio(1);
#pragma unroll
        for (int fm = 0; fm < 4; ++fm) {
            acc[fm][0] = __builtin_amdgcn_mfma_f32_16x16x32_bf16(aA[fm*2+0], brg[0][0], acc[fm][0], 0, 0, 0);
            acc[fm][0] = __builtin_amdgcn_mfma_f32_16x16x32_bf16(aA[fm*2+1], brg[0][1], acc[fm][0], 0, 0, 0);
        }
        __builtin_amdgcn_s_setprio(0); SCHEDB(); BARRIER();

        // ---------- phase 1: read A-half1; stage A2,A3; MFMA (m0,n1)
        short8 aB[8];
#pragma unroll
        for (int fm = 0; fm < 4; ++fm) {
            const int row = arow + 64 + fm * 16;
            aB[fm * 2 + 0] = *(const short8*)&Abuf[buf * 16384 + row * 64 + ko0];
            aB[fm * 2 + 1] = *(const short8*)&Abuf[buf * 16384 + row * 64 + ko1];
        }
        if (st) { stageA(nbuf, t + 2, sA2, 2); stageA(nbuf, t + 2, sA3, 3); }
        BARRIER(); SCHEDB();
        __builtin_amdgcn_s_setprio(1);
#pragma unroll
        for (int fm = 0; fm < 4; ++fm) {
            acc[fm][1] = __builtin_amdgcn_mfma_f32_16x16x32_bf16(aA[fm*2+0], brg[1][0], acc[fm][1], 0, 0, 0);
            acc[fm][1] = __builtin_amdgcn_mfma_f32_16x16x32_bf16(aA[fm*2+1], brg[1][1], acc[fm][1], 0, 0, 0);
        }
        __builtin_amdgcn_s_setprio(0); SCHEDB(); BARRIER();

        // ---------- phase 2: stage B0; MFMA (m1,n0)
        if (st) stageB(nbuf, t + 2, 0);
        BARRIER(); SCHEDB();
        __builtin_amdgcn_s_setprio(1);
#pragma unroll
        for (int fm = 0; fm < 4; ++fm) {
            acc[4+fm][0] = __builtin_amdgcn_mfma_f32_16x16x32_bf16(aB[fm*2+0], brg[0][0], acc[4+fm][0], 0, 0, 0);
            acc[4+fm][0] = __builtin_amdgcn_mfma_f32_16x16x32_bf16(aB[fm*2+1], brg[0][1], acc[4+fm][0], 0, 0, 0);
        }
        __builtin_amdgcn_s_setprio(0); SCHEDB(); BARRIER();

        // ---------- phase 3: stage B1; MFMA (m1,n1); tile-granular vmcnt
        if (st) stageB(nbuf, t + 2, 1);
        BARRIER(); SCHEDB();
        __builtin_amdgcn_s_setprio(1);
#pragma unroll
        for (int fm = 0; fm < 4; ++fm) {
            acc[4+fm][1] = __builtin_amdgcn_mfma_f32_16x16x32_bf16(aB[fm*2+0], brg[1][0], acc[4+fm][1], 0, 0, 0);
            acc[4+fm][1] = __builtin_amdgcn_mfma_f32_16x16x32_bf16(aB[fm*2+1], brg[1][1], acc[4+fm][1], 0, 0, 0);
        }
        __builtin_amdgcn_s_setprio(0); SCHEDB();
        if (t + 1 < KT) {
            if (st) WAITV6(); else WAITV0();   // next tile's 6 loads complete
            BARRIER();
        }
        buf = (buf == 2) ? 0 : buf + 1;
    }

    // ---- epilogue: C/D layout col=lane&15, row=quad*4+reg
#pragma unroll
    for (int FM = 0; FM < 8; ++FM) {
        const int rowb = ib + wm * 128 + FM * 16 + quad * 4;
#pragma unroll
        for (int r = 0; r < 4; ++r) {
            const int gi = rowb + r;
            if (SCATTER) {
                const int slotI = e * CAP + gi;
                const int tok = slot_token[slotI];
                if (tok >= 0) {
                    const float gsc = slot_gate[slotI];
                    float* Out = (float*)Outv;
#pragma unroll
                    for (int fn = 0; fn < 2; ++fn) {
                        const int gn = nb + wn * 32 + fn * 16 + l15;
                        Out[(size_t)tok * N + gn] = gsc * acc[FM][fn][r];
                    }
                }
            } else {
                unsigned short* Out = (unsigned short*)Outv;
#pragma unroll
                for (int fn = 0; fn < 2; ++fn) {
                    const int gn = nb + wn * 32 + fn * 16 + l15;
                    Out[((size_t)e * CAP + gi) * N + gn] = f2b(fmaxf(acc[FM][fn][r], 0.f));
                }
            }
        }
    }
}

// ---------------- Kernel 2 (fallback): scan / slot assignment / l_aux ------
__global__ __launch_bounds__(256) void scan_kernel(
    const float* __restrict__ gates8, const int* __restrict__ token_expert,
    int* __restrict__ slot_token, float* __restrict__ slot_gate,
    float* __restrict__ laux_out)
{
    __shared__ int   cnt[256][EXP];
    __shared__ float fsum[256][EXP];
    __shared__ int   tot[EXP];
    const int t = threadIdx.x;

    for (int i = t; i < EXP * CAP; i += 256) slot_token[i] = -1;

    int local[EXP];
#pragma unroll
    for (int e = 0; e < EXP; ++e) local[e] = 0;
    const int s0 = t * 32;
    for (int j = 0; j < 32; ++j) local[token_expert[s0 + j]]++;
#pragma unroll
    for (int e = 0; e < EXP; ++e) cnt[t][e] = local[e];
    __syncthreads();

    if (t < EXP) {
        int run = 0;
        for (int i = 0; i < 256; ++i) { int v = cnt[i][t]; cnt[i][t] = run; run += v; }
        tot[t] = run;
    }
    __syncthreads();

    int off[EXP];
#pragma unroll
    for (int e = 0; e < EXP; ++e) off[e] = cnt[t][e];
    for (int j = 0; j < 32; ++j) {
        int s = s0 + j;
        int e = token_expert[s];
        int loc = off[e]++;
        if (loc < CAP) {
            int slot = e * CAP + loc;
            slot_token[slot] = s;
            slot_gate[slot]  = gates8[(size_t)s * EXP + e];
        }
    }

    float ms[EXP];
#pragma unroll
    for (int e = 0; e < EXP; ++e) ms[e] = 0.f;
    for (int j = 0; j < 32; ++j) {
        const float* g = gates8 + (size_t)(s0 + j) * EXP;
#pragma unroll
        for (int e = 0; e < EXP; ++e) ms[e] += g[e];
    }
#pragma unroll
    for (int e = 0; e < EXP; ++e) fsum[t][e] = ms[e];
    __syncthreads();
    for (int st = 128; st > 0; st >>= 1) {
        if (t < st) {
#pragma unroll
            for (int e = 0; e < EXP; ++e) fsum[t][e] += fsum[t + st][e];
        }
        __syncthreads();
    }
    if (t == 0) {
        float l = 0.f;
#pragma unroll
        for (int e = 0; e < EXP; ++e)
            l += (fsum[0][e] / (float)S_TOK) * ((float)tot[e] / (float)S_TOK);
        laux_out[0] = l * (float)EXP;
    }
}

// ---------------- Fallback (proven): fused-cvt GEMM ------------------------
template<int KSTEPS, int N, bool GATHER, bool SCATTER>
__global__ __launch_bounds__(256) void ffn_gemm_slow(
    const void* __restrict__ Agv, const float* __restrict__ Bg,
    void* __restrict__ Outv,
    const int* __restrict__ slot_token, const float* __restrict__ slot_gate)
{
    constexpr int K = KSTEPS * 32;
    const int e  = blockIdx.z;
    const int ib = blockIdx.y * 128;
    const int nb = blockIdx.x * 128;
    const int t  = threadIdx.x;

    __shared__ unsigned short As[128 * 40];
    __shared__ unsigned short Bs[32 * 136];

    const float* B = Bg + (size_t)e * K * N;
    const int arow  = t >> 1;
    const int ahalf = t & 1;
    const float* ArowF = nullptr;
    const unsigned short* ArowH = nullptr;
    bool avalid = true;
    if (GATHER) {
        int tok = slot_token[e * CAP + ib + arow];
        avalid = (tok >= 0);
        ArowF = (const float*)Agv + (size_t)(avalid ? tok : 0) * K;
    } else {
        ArowH = (const unsigned short*)Agv + ((size_t)e * CAP + ib + arow) * K;
    }
    const int bk  = t >> 3;
    const int bn0 = (t & 7) * 16;
    const float* Bptr = B + (size_t)bk * N + nb + bn0;

    const int lane = t & 63, wave = t >> 6;
    const int quad = lane >> 4, l15 = lane & 15;
    const int wr = wave >> 1, wc = wave & 1;

    floatx4 acc[4][4];
#pragma unroll
    for (int r = 0; r < 4; ++r)
#pragma unroll
        for (int c = 0; c < 4; ++c)
            acc[r][c] = (floatx4){0.f, 0.f, 0.f, 0.f};

    for (int kb = 0; kb < KSTEPS; ++kb) {
        const int k0 = kb * 32;
        unsigned short av[16];
        if (GATHER) {
            if (avalid) {
                const float4* p = (const float4*)(ArowF + k0 + ahalf * 16);
                float4 f0 = p[0], f1 = p[1], f2 = p[2], f3 = p[3];
                const float fa[16] = {f0.x,f0.y,f0.z,f0.w, f1.x,f1.y,f1.z,f1.w,
                                      f2.x,f2.y,f2.z,f2.w, f3.x,f3.y,f3.z,f3.w};
#pragma unroll
                for (int j = 0; j < 16; ++j) av[j] = f2b(fa[j]);
            } else {
#pragma unroll
                for (int j = 0; j < 16; ++j) av[j] = 0;
            }
        } else {
            const int4* p = (const int4*)(ArowH + k0 + ahalf * 16);
            *(int4*)(av)     = p[0];
            *(int4*)(av + 8) = p[1];
        }
        unsigned short bv[16];
        {
            const float4* q = (const float4*)(Bptr + (size_t)k0 * N);
            float4 f0 = q[0], f1 = q[1], f2 = q[2], f3 = q[3];
            const float fb[16] = {f0.x,f0.y,f0.z,f0.w, f1.x,f1.y,f1.z,f1.w,
                                  f2.x,f2.y,f2.z,f2.w, f3.x,f3.y,f3.z,f3.w};
#pragma unroll
            for (int j = 0; j < 16; ++j) bv[j] = f2b(fb[j]);
        }

        *(int4*)&As[arow * 40 + ahalf * 16]     = *(int4*)(av);
        *(int4*)&As[arow * 40 + ahalf * 16 + 8] = *(int4*)(av + 8);
        *(int4*)&Bs[bk * 136 + bn0]             = *(int4*)(bv);
        *(int4*)&Bs[bk * 136 + bn0 + 8]         = *(int4*)(bv + 8);
        __syncthreads();

        short8 af[4];
#pragma unroll
        for (int r = 0; r < 4; ++r)
            af[r] = *(const short8*)&As[(wr * 64 + r * 16 + l15) * 40 + quad * 8];
        short8 bfr[4];
#pragma unroll
        for (int c = 0; c < 4; ++c) {
#pragma unroll
            for (int j = 0; j < 8; ++j)
                bfr[c][j] = (short)Bs[(quad * 8 + j) * 136 + wc * 64 + c * 16 + l15];
        }
#pragma unroll
        for (int r = 0; r < 4; ++r)
#pragma unroll
            for (int c = 0; c < 4; ++c)
                acc[r][c] = __builtin_amdgcn_mfma_f32_16x16x32_bf16(af[r], bfr[c], acc[r][c], 0, 0, 0);
        __syncthreads();
    }

#pragma unroll
    for (int r = 0; r < 4; ++r) {
#pragma unroll
        for (int reg = 0; reg < 4; ++reg) {
            const int gi = ib + wr * 64 + r * 16 + quad * 4 + reg;
            if (SCATTER) {
                const int slot = e * CAP + gi;
                const int tok = slot_token[slot];
                if (tok >= 0) {
                    const float gsc = slot_gate[slot];
                    float* Out = (float*)Outv;
#pragma unroll
                    for (int c = 0; c < 4; ++c) {
                        const int gn = nb + wc * 64 + c * 16 + l15;
                        Out[(size_t)tok * N + gn] = gsc * acc[r][c][reg];
                    }
                }
            } else {
                unsigned short* Out = (unsigned short*)Outv;
#pragma unroll
                for (int c = 0; c < 4; ++c) {
                    const int gn = nb + wc * 64 + c * 16 + l15;
                    Out[((size_t)e * CAP + gi) * N + gn] = f2b(fmaxf(acc[r][c][reg], 0.f));
                }
            }
        }
    }
}

extern "C" void kernel_launch(void* const* d_in, const int* in_sizes, int n_in,
                              void* d_out, int out_size, void* d_ws, size_t ws_size,
                              hipStream_t stream)
{
    const float* x  = (const float*)d_in[0];   // [8192,1024] fp32
    const float* wg = (const float*)d_in[1];   // [1024,8]    fp32
    const float* w1 = (const float*)d_in[2];   // [8,1024,4096] fp32
    const float* w2 = (const float*)d_in[3];   // [8,4096,1024] fp32
    float* out = (float*)d_out;                // 8388608 out + 1 l_aux, fp32
    float* laux = out + (size_t)S_TOK * MDIM;

    char* ws = (char*)d_ws;
    float* gates8       = (float*)(ws);                 // 256 KB
    int*   token_expert = (int*)(ws + 262144);          // 32 KB
    int*   slot_token   = (int*)(ws + 294912);          // 32 KB
    float* slot_gate    = (float*)(ws + 327680);        // 32 KB
    unsigned short* xb16 = (unsigned short*)(ws + 360448);      // 16 MB
    unsigned short* h    = (unsigned short*)(ws + 17137664);    // 64 MB
    unsigned short* W1T  = (unsigned short*)(ws + 84246528);    // 64 MB
    unsigned short* W2T  = (unsigned short*)(ws + 151355392);   // 64 MB (wide only)

    const size_t FAST_NEED = 151355392ull;               // through W1T
    const size_t WIDE_NEED = 218464256ull;               // + W2T

    if (ws_size >= FAST_NEED) {
        const bool wide = (ws_size >= WIDE_NEED);

        static bool tried = false, ok8 = false;
        if (!tried) {
            tried = true;
            ok8 = (hipFuncSetAttribute((const void*)ffn_gemm_8p<16, HDIM, false, true>,
                       hipFuncAttributeMaxDynamicSharedMemorySize, 147456) == hipSuccess)
               && (hipFuncSetAttribute((const void*)ffn_gemm_8p<64, MDIM, true, false>,
                       hipFuncAttributeMaxDynamicSharedMemorySize, 147456) == hipSuccess);
        }

        gate_kernel<<<dim3(S_TOK / 4), dim3(256), 0, stream>>>(x, wg, gates8, token_expert, xb16);

        const int nblk = 1 + 2048 + 8192 + (wide ? 8192 : 0);
        mega_prep<<<dim3(nblk), dim3(256), 0, stream>>>(
            gates8, token_expert, slot_token, slot_gate, laux,
            w1, w2, W1T, wide ? W2T : W1T, out);

        if (ok8) {
            ffn_gemm_8p<16, HDIM, false, true><<<dim3((HDIM/128)*(CAP/256), 1, EXP), dim3(512), 147456, stream>>>(
                xb16, W1T, h, slot_token, slot_gate);
            if (!wide)
                transpose_cvt<<<dim3(MDIM / 64, HDIM / 64, EXP), dim3(256), 0, stream>>>(w2, W1T, HDIM, MDIM);
            ffn_gemm_8p<64, MDIM, true, false><<<dim3((MDIM/128)*(CAP/256), 1, EXP), dim3(512), 147456, stream>>>(
                h, wide ? W2T : W1T, out, slot_token, slot_gate);
        } else {
            // proven fallback: fused-cvt GEMMs straight from fp32 weights
            ffn_gemm_slow<32, HDIM, true, false><<<dim3(HDIM / 128, CAP / 128, EXP), dim3(256), 0, stream>>>(
                x, w1, h, slot_token, slot_gate);
            ffn_gemm_slow<128, MDIM, false, true><<<dim3(MDIM / 128, CAP / 128, EXP), dim3(256), 0, stream>>>(
                h, w2, out, slot_token, slot_gate);
        }
    } else {
        hipMemsetAsync(d_out, 0, (size_t)out_size * 4, stream);
        gate_kernel<<<dim3(S_TOK / 4), dim3(256), 0, stream>>>(x, wg, gates8, token_expert, nullptr);
        scan_kernel<<<dim3(1), dim3(256), 0, stream>>>(gates8, token_expert, slot_token, slot_gate, laux);
        unsigned short* hs = (unsigned short*)(ws + 360448);    // 64 MB
        ffn_gemm_slow<32, HDIM, true, false><<<dim3(HDIM / 128, CAP / 128, EXP), dim3(256), 0, stream>>>(
            x, w1, hs, slot_token, slot_gate);
        ffn_gemm_slow<128, MDIM, false, true><<<dim3(MDIM / 128, CAP / 128, EXP), dim3(256), 0, stream>>>(
            hs, w2, out, slot_token, slot_gate);
    }
}